// Round 5
// baseline (158.408 us; speedup 1.0000x reference)
//
#include <hip/hip_runtime.h>
#include <math.h>

#define NEGV  (-1e30f)
#define LOG2E 1.44269504088896340736f
#define LN2   0.69314718055994530942f

typedef __attribute__((ext_vector_type(8))) short short8;
typedef __attribute__((ext_vector_type(4))) float f32x4;

// Single-instruction base-2 transcendentals (v_exp_f32 / v_log_f32).
// NOTE: __exp2f/__log2f are NOT defined in HIP device headers (glibc macro
// collision) — use the amdgcn builtins directly.
__device__ __forceinline__ float exp2_fast(float a) { return __builtin_amdgcn_exp2f(a); }
__device__ __forceinline__ float log2_fast(float a) { return __builtin_amdgcn_logf(a); }

// Split 8 fp32 into hi/lo bf16 fragments (truncation split: x ~= hi + lo;
// 3-MFMA products hh+hl+lh give ~2^-16 relative error, near-fp32).
__device__ __forceinline__ void split8(float4 a, float4 b, short8& hi, short8& lo) {
    float f[8] = {a.x, a.y, a.z, a.w, b.x, b.y, b.z, b.w};
#pragma unroll
    for (int j = 0; j < 8; ++j) {
        const unsigned u = __float_as_uint(f[j]);
        hi[j] = (short)(u >> 16);
        const float hf = __uint_as_float(u & 0xFFFF0000u);
        const float lf = f[j] - hf;
        lo[j] = (short)(__float_as_uint(lf) >> 16);
    }
}

// Mask + two-phase log-softmax/logsumexp for one batch's accumulators.
// All values are in the log2 domain (theta pre-scaled by LOG2E).
// acc layout (m89): col = lane&15 = l_local(nt), row = (lane>>4)*4 + i = g_local.
__device__ __forceinline__ void finish(f32x4* acc, const float* wg, int len,
                                       int lane, float* rm, float* rs)
{
    const int c15 = lane & 15;
    const int q   = lane >> 4;

    // mask invalid l once: exp2(NEGV - m) == 0 exactly
#pragma unroll
    for (int nt = 0; nt < 8; ++nt) {
        const bool v = ((nt << 4) + c15) < len;
#pragma unroll
        for (int i = 0; i < 4; ++i) acc[nt][i] = v ? acc[nt][i] : NEGV;
    }

    // phase 1: lse2 over l per g (wave-local: in-lane over nt + shfl {1,2,4,8})
    float c4[4];
#pragma unroll
    for (int i = 0; i < 4; ++i) {
        float m = acc[0][i];
#pragma unroll
        for (int nt = 1; nt < 8; ++nt) m = fmaxf(m, acc[nt][i]);
#pragma unroll
        for (int s = 1; s < 16; s <<= 1) m = fmaxf(m, __shfl_xor(m, s, 64));
        float e = 0.f;
#pragma unroll
        for (int nt = 0; nt < 8; ++nt) e += exp2_fast(acc[nt][i] - m);
#pragma unroll
        for (int s = 1; s < 16; s <<= 1) e += __shfl_xor(e, s, 64);
        c4[i] = wg[i] - (m + log2_fast(e));
    }

    // phase 2: partial lse2 over this wave's 16 g per l (in-lane + shfl {16,32})
#pragma unroll
    for (int nt = 0; nt < 8; ++nt) {
        const float t0 = acc[nt][0] + c4[0];
        const float t1 = acc[nt][1] + c4[1];
        const float t2 = acc[nt][2] + c4[2];
        const float t3 = acc[nt][3] + c4[3];
        float m2 = fmaxf(fmaxf(t0, t1), fmaxf(t2, t3));
        m2 = fmaxf(m2, __shfl_xor(m2, 16, 64));
        m2 = fmaxf(m2, __shfl_xor(m2, 32, 64));
        float s2 = exp2_fast(t0 - m2) + exp2_fast(t1 - m2)
                 + exp2_fast(t2 - m2) + exp2_fast(t3 - m2);
        s2 += __shfl_xor(s2, 16, 64);
        s2 += __shfl_xor(s2, 32, 64);
        if ((nt >> 1) == q) {           // static reg index, predicated write
            rm[(nt << 4) + c15] = m2;
            rs[(nt << 4) + c15] = s2;
        }
    }
}

// One block = 2 batches, 4 waves. Wave w owns g in [16w,16w+16) (MFMA M),
// all 128 l (8 N-tiles), for BOTH batches -> two independent dependency
// chains per thread for latency hiding. 16x16x32 bf16 MFMA, hi/lo split.
__global__ __launch_bounds__(256, 3) void mixed_logit_kernel(
    const float* __restrict__ x,      // [B,128,64]
    const int*   __restrict__ lens,   // [B]
    const float* __restrict__ theta,  // [64,64]
    const float* __restrict__ mw,     // [64]
    float* __restrict__ out,          // [B,128]
    int B)
{
    __shared__ float red_m[2][4][128];
    __shared__ float red_s[2][4][128];

    const int tid  = threadIdx.x;
    const int lane = tid & 63;
    const int w    = tid >> 6;
    const int c15  = lane & 15;
    const int q    = lane >> 4;
    const int b0   = blockIdx.x << 1;
    const int b1   = (b0 + 1 < B) ? b0 + 1 : b0;

    const int len0 = lens[b0];
    const int len1 = lens[b1];

    // ---- theta A-fragments, scaled by LOG2E (log2-domain GEMM), hi/lo split ----
    short8 th_hi[2], th_lo[2];
    {
        const float* tr = theta + (size_t)((w << 4) + c15) * 64 + (q << 3);
#pragma unroll
        for (int kt = 0; kt < 2; ++kt) {
            float4 a = *(const float4*)(tr + kt * 32);
            float4 c = *(const float4*)(tr + kt * 32 + 4);
            a.x *= LOG2E; a.y *= LOG2E; a.z *= LOG2E; a.w *= LOG2E;
            c.x *= LOG2E; c.y *= LOG2E; c.z *= LOG2E; c.w *= LOG2E;
            split8(a, c, th_hi[kt], th_lo[kt]);
        }
    }

    // ---- mixture log-softmax constant (log2 domain) ----
    float wg[4];
    {
        const float mwl = mw[lane];
        float mmax = mwl;
#pragma unroll
        for (int s = 32; s >= 1; s >>= 1) mmax = fmaxf(mmax, __shfl_xor(mmax, s, 64));
        float me = __expf(mwl - mmax);
#pragma unroll
        for (int s = 32; s >= 1; s >>= 1) me += __shfl_xor(me, s, 64);
        const float logZ = mmax + __logf(me);
#pragma unroll
        for (int i = 0; i < 4; ++i)
            wg[i] = (mw[(w << 4) + (q << 2) + i] - logZ) * LOG2E;
    }

    // ---- GEMM: both batches interleaved; 8 N-tiles x 2 K-tiles x 3 MFMA each ----
    f32x4 acc0[8], acc1[8];
#pragma unroll
    for (int nt = 0; nt < 8; ++nt) {
        acc0[nt] = (f32x4){0.f, 0.f, 0.f, 0.f};
        acc1[nt] = (f32x4){0.f, 0.f, 0.f, 0.f};
    }

    const float* xb0 = x + (size_t)b0 * (128 * 64);
    const float* xb1 = x + (size_t)b1 * (128 * 64);
#pragma unroll
    for (int nt = 0; nt < 8; ++nt) {
        const size_t ro = (size_t)((nt << 4) + c15) * 64 + (q << 3);
        const float* xr0 = xb0 + ro;
        const float* xr1 = xb1 + ro;
        const float4 p0 = *(const float4*)(xr0);
        const float4 p1 = *(const float4*)(xr0 + 4);
        const float4 p2 = *(const float4*)(xr0 + 32);
        const float4 p3 = *(const float4*)(xr0 + 36);
        const float4 r0 = *(const float4*)(xr1);
        const float4 r1 = *(const float4*)(xr1 + 4);
        const float4 r2 = *(const float4*)(xr1 + 32);
        const float4 r3 = *(const float4*)(xr1 + 36);
        short8 h00, l00, h01, l01, h10, l10, h11, l11;
        split8(p0, p1, h00, l00);
        split8(p2, p3, h01, l01);
        split8(r0, r1, h10, l10);
        split8(r2, r3, h11, l11);
        acc0[nt] = __builtin_amdgcn_mfma_f32_16x16x32_bf16(th_hi[0], h00, acc0[nt], 0, 0, 0);
        acc1[nt] = __builtin_amdgcn_mfma_f32_16x16x32_bf16(th_hi[0], h10, acc1[nt], 0, 0, 0);
        acc0[nt] = __builtin_amdgcn_mfma_f32_16x16x32_bf16(th_hi[0], l00, acc0[nt], 0, 0, 0);
        acc1[nt] = __builtin_amdgcn_mfma_f32_16x16x32_bf16(th_hi[0], l10, acc1[nt], 0, 0, 0);
        acc0[nt] = __builtin_amdgcn_mfma_f32_16x16x32_bf16(th_lo[0], h00, acc0[nt], 0, 0, 0);
        acc1[nt] = __builtin_amdgcn_mfma_f32_16x16x32_bf16(th_lo[0], h10, acc1[nt], 0, 0, 0);
        acc0[nt] = __builtin_amdgcn_mfma_f32_16x16x32_bf16(th_hi[1], h01, acc0[nt], 0, 0, 0);
        acc1[nt] = __builtin_amdgcn_mfma_f32_16x16x32_bf16(th_hi[1], h11, acc1[nt], 0, 0, 0);
        acc0[nt] = __builtin_amdgcn_mfma_f32_16x16x32_bf16(th_hi[1], l01, acc0[nt], 0, 0, 0);
        acc1[nt] = __builtin_amdgcn_mfma_f32_16x16x32_bf16(th_hi[1], l11, acc1[nt], 0, 0, 0);
        acc0[nt] = __builtin_amdgcn_mfma_f32_16x16x32_bf16(th_lo[1], h01, acc0[nt], 0, 0, 0);
        acc1[nt] = __builtin_amdgcn_mfma_f32_16x16x32_bf16(th_lo[1], h11, acc1[nt], 0, 0, 0);
    }

    // ---- two independent softmax chains (compiler interleaves) ----
    finish(acc0, wg, len0, lane, red_m[0][w], red_s[0][w]);
    finish(acc1, wg, len1, lane, red_m[1][w], red_s[1][w]);
    __syncthreads();

    // ---- final: all 256 threads busy; convert log2 -> ln; finite sentinel ----
    {
        const int sel = tid >> 7;
        const int l   = tid & 127;
        const int bb  = sel ? b1 : b0;
        const int ln  = sel ? len1 : len0;
        float M = red_m[sel][0][l];
        M = fmaxf(M, red_m[sel][1][l]);
        M = fmaxf(M, red_m[sel][2][l]);
        M = fmaxf(M, red_m[sel][3][l]);
        const float S = red_s[sel][0][l] * exp2_fast(red_m[sel][0][l] - M)
                      + red_s[sel][1][l] * exp2_fast(red_m[sel][1][l] - M)
                      + red_s[sel][2][l] * exp2_fast(red_m[sel][2][l] - M)
                      + red_s[sel][3][l] * exp2_fast(red_m[sel][3][l] - M);
        const float o = LN2 * (M + log2_fast(S));
        out[(size_t)bb * 128 + l] = (l < ln) ? o : NEGV;
    }
}

extern "C" void kernel_launch(void* const* d_in, const int* in_sizes, int n_in,
                              void* d_out, int out_size, void* d_ws, size_t ws_size,
                              hipStream_t stream) {
    const float* x     = (const float*)d_in[0];
    const int*   lens  = (const int*)d_in[1];
    const float* theta = (const float*)d_in[2];
    const float* mw    = (const float*)d_in[3];
    float* out = (float*)d_out;
    const int B = in_sizes[1];  // 8192
    mixed_logit_kernel<<<(B + 1) / 2, 256, 0, stream>>>(x, lens, theta, mw, out, B);
}

// Round 6
// 63.358 us; speedup vs baseline: 2.5002x; 2.5002x over previous
//
#include <hip/hip_runtime.h>
#include <math.h>

#define NEGV  (-1e30f)
#define LOG2E 1.44269504088896340736f
#define LN2   0.69314718055994530942f

typedef __attribute__((ext_vector_type(8))) short short8;
typedef __attribute__((ext_vector_type(4))) float f32x4;

// Single-instruction base-2 transcendentals (v_exp_f32 / v_log_f32).
__device__ __forceinline__ float exp2_fast(float a) { return __builtin_amdgcn_exp2f(a); }
__device__ __forceinline__ float log2_fast(float a) { return __builtin_amdgcn_logf(a); }

// Split 8 fp32 into hi/lo bf16 (truncation split: x ~= hi + lo; 3-MFMA
// products hh+hl+lh give ~2^-16 relative error, near-fp32).
__device__ __forceinline__ void split8(float4 a, float4 b, short8& hi, short8& lo) {
    float f[8] = {a.x, a.y, a.z, a.w, b.x, b.y, b.z, b.w};
#pragma unroll
    for (int j = 0; j < 8; ++j) {
        const unsigned u = __float_as_uint(f[j]);
        hi[j] = (short)(u >> 16);
        const float hf = __uint_as_float(u & 0xFFFF0000u);
        const float lf = f[j] - hf;
        lo[j] = (short)(__float_as_uint(lf) >> 16);
    }
}

// ws layout (floats): [0..63] wg_full[g] = (mw[g]-logZ)*LOG2E
//                     [64.. ] theta frags: slot s = ((w*2+kt)*2 + h), h=0 hi,1 lo
//                             addr = 64 + (s*64 + lane)*4   (short8 = 4 floats)
#define WS_FLOATS_NEEDED (64 + 16 * 64 * 4)

__global__ void prep_kernel(const float* __restrict__ theta,
                            const float* __restrict__ mw,
                            float* __restrict__ ws)
{
    const int lane = threadIdx.x;  // 64 threads, 1 wave
    const int c15  = lane & 15;
    const int q    = lane >> 4;

    // mixture log-softmax -> wg_full (log2 domain)
    const float v = mw[lane];
    float m = v;
#pragma unroll
    for (int s = 32; s >= 1; s >>= 1) m = fmaxf(m, __shfl_xor(m, s, 64));
    float e = __expf(v - m);
#pragma unroll
    for (int s = 32; s >= 1; s >>= 1) e += __shfl_xor(e, s, 64);
    const float logZ = m + __logf(e);
    ws[lane] = (v - logZ) * LOG2E;

    // theta fragments, scaled by LOG2E, hi/lo split
#pragma unroll
    for (int w = 0; w < 4; ++w) {
        const float* tr = theta + (size_t)((w << 4) + c15) * 64 + (q << 3);
#pragma unroll
        for (int kt = 0; kt < 2; ++kt) {
            float4 a = *(const float4*)(tr + kt * 32);
            float4 c = *(const float4*)(tr + kt * 32 + 4);
            a.x *= LOG2E; a.y *= LOG2E; a.z *= LOG2E; a.w *= LOG2E;
            c.x *= LOG2E; c.y *= LOG2E; c.z *= LOG2E; c.w *= LOG2E;
            short8 hi, lo;
            split8(a, c, hi, lo);
            const int s = ((w << 1) + kt) << 1;
            *(short8*)&ws[64 + ((s + 0) * 64 + lane) * 4] = hi;
            *(short8*)&ws[64 + ((s + 1) * 64 + lane) * 4] = lo;
        }
    }
}

// Mask + two-phase log-softmax/logsumexp (log2 domain throughout).
// acc layout (m89): col = lane&15 = l_local(nt), row = (lane>>4)*4 + i = g_local.
__device__ __forceinline__ void finish(f32x4* acc, const float* wg, int len,
                                       int lane, float* rm, float* rs)
{
    const int c15 = lane & 15;
    const int q   = lane >> 4;

#pragma unroll
    for (int nt = 0; nt < 8; ++nt) {
        const bool v = ((nt << 4) + c15) < len;
#pragma unroll
        for (int i = 0; i < 4; ++i) acc[nt][i] = v ? acc[nt][i] : NEGV;
    }

    // phase 1: lse2 over l per g (in-lane over nt + shfl {1,2,4,8})
    float c4[4];
#pragma unroll
    for (int i = 0; i < 4; ++i) {
        float m = acc[0][i];
#pragma unroll
        for (int nt = 1; nt < 8; ++nt) m = fmaxf(m, acc[nt][i]);
#pragma unroll
        for (int s = 1; s < 16; s <<= 1) m = fmaxf(m, __shfl_xor(m, s, 64));
        float e = 0.f;
#pragma unroll
        for (int nt = 0; nt < 8; ++nt) e += exp2_fast(acc[nt][i] - m);
#pragma unroll
        for (int s = 1; s < 16; s <<= 1) e += __shfl_xor(e, s, 64);
        c4[i] = wg[i] - (m + log2_fast(e));
    }

    // phase 2: partial lse2 over this wave's 16 g per l (in-lane + shfl {16,32})
#pragma unroll
    for (int nt = 0; nt < 8; ++nt) {
        const float t0 = acc[nt][0] + c4[0];
        const float t1 = acc[nt][1] + c4[1];
        const float t2 = acc[nt][2] + c4[2];
        const float t3 = acc[nt][3] + c4[3];
        float m2 = fmaxf(fmaxf(t0, t1), fmaxf(t2, t3));
        m2 = fmaxf(m2, __shfl_xor(m2, 16, 64));
        m2 = fmaxf(m2, __shfl_xor(m2, 32, 64));
        float s2 = exp2_fast(t0 - m2) + exp2_fast(t1 - m2)
                 + exp2_fast(t2 - m2) + exp2_fast(t3 - m2);
        s2 += __shfl_xor(s2, 16, 64);
        s2 += __shfl_xor(s2, 32, 64);
        if ((nt >> 1) == q) {           // static reg index, predicated write
            rm[(nt << 4) + c15] = m2;
            rs[(nt << 4) + c15] = s2;
        }
    }
}

// One block = one batch, 4 waves. Wave w owns g in [16w,16w+16).
// x staged through LDS: coalesced float4 global loads, pre-split bf16 hi/lo,
// row stride 272 B (= 17 x 16B, odd quad multiple -> both ds_write_b128 and
// fragment ds_read_b128 hit exactly 8 lanes/quad = conflict-free b128 floor).
// Row layout: [64 hi bf16 (128B) | 64 lo bf16 (128B) | 16B pad].
template<bool USE_WS>
__global__ __launch_bounds__(256, 4) void mixed_logit_kernel(
    const float* __restrict__ x,      // [B,128,64]
    const int*   __restrict__ lens,   // [B]
    const float* __restrict__ theta,  // [64,64]
    const float* __restrict__ mw,     // [64]
    const float* __restrict__ ws,     // prep output (if USE_WS)
    float* __restrict__ out)          // [B,128]
{
    __shared__ __align__(16) unsigned char xbuf[128 * 272];  // 34816 B
    __shared__ float red_m[4][128];
    __shared__ float red_s[4][128];

    const int tid  = threadIdx.x;
    const int lane = tid & 63;
    const int w    = tid >> 6;
    const int c15  = lane & 15;
    const int q    = lane >> 4;
    const int b    = blockIdx.x;
    const int len  = lens[b];

    // ---- stage x: 1024 float4-pairs, 4 per thread, coalesced 32B/lane ----
    const float4* xp = (const float4*)(x + (size_t)b * 8192);
#pragma unroll
    for (int i = 0; i < 4; ++i) {
        const int j2  = (i << 8) + tid;   // pair index: row = j2>>3, p8 = j2&7
        const int row = j2 >> 3;
        const int p8  = j2 & 7;
        const float4 a = xp[j2 * 2];
        const float4 c = xp[j2 * 2 + 1];
        short8 hi, lo;
        split8(a, c, hi, lo);
        unsigned char* base = xbuf + row * 272 + p8 * 16;
        *(short8*)(base)       = hi;
        *(short8*)(base + 128) = lo;
    }

    // ---- theta fragments + mixture constants ----
    short8 th_hi[2], th_lo[2];
    float wg[4];
    if constexpr (USE_WS) {
#pragma unroll
        for (int kt = 0; kt < 2; ++kt) {
            const int s = ((w << 1) + kt) << 1;
            th_hi[kt] = *(const short8*)&ws[64 + ((s + 0) * 64 + lane) * 4];
            th_lo[kt] = *(const short8*)&ws[64 + ((s + 1) * 64 + lane) * 4];
        }
        const float4 wv = *(const float4*)&ws[(w << 4) + (q << 2)];
        wg[0] = wv.x; wg[1] = wv.y; wg[2] = wv.z; wg[3] = wv.w;
    } else {
        const float* tr = theta + (size_t)((w << 4) + c15) * 64 + (q << 3);
#pragma unroll
        for (int kt = 0; kt < 2; ++kt) {
            float4 a = *(const float4*)(tr + kt * 32);
            float4 c = *(const float4*)(tr + kt * 32 + 4);
            a.x *= LOG2E; a.y *= LOG2E; a.z *= LOG2E; a.w *= LOG2E;
            c.x *= LOG2E; c.y *= LOG2E; c.z *= LOG2E; c.w *= LOG2E;
            split8(a, c, th_hi[kt], th_lo[kt]);
        }
        const float mwl = mw[lane];
        float mmax = mwl;
#pragma unroll
        for (int s = 32; s >= 1; s >>= 1) mmax = fmaxf(mmax, __shfl_xor(mmax, s, 64));
        float me = __expf(mwl - mmax);
#pragma unroll
        for (int s = 32; s >= 1; s >>= 1) me += __shfl_xor(me, s, 64);
        const float logZ = mmax + __logf(me);
#pragma unroll
        for (int i = 0; i < 4; ++i)
            wg[i] = (mw[(w << 4) + (q << 2) + i] - logZ) * LOG2E;
    }

    __syncthreads();

    // ---- GEMM: fragments from LDS (conflict-free b128), 6 MFMA per nt ----
    f32x4 acc[8];
#pragma unroll
    for (int nt = 0; nt < 8; ++nt) acc[nt] = (f32x4){0.f, 0.f, 0.f, 0.f};

#pragma unroll
    for (int nt = 0; nt < 8; ++nt) {
        const unsigned char* rb = xbuf + ((nt << 4) + c15) * 272 + (q << 4);
        const short8 xh0 = *(const short8*)(rb);
        const short8 xh1 = *(const short8*)(rb + 64);
        const short8 xl0 = *(const short8*)(rb + 128);
        const short8 xl1 = *(const short8*)(rb + 192);
        acc[nt] = __builtin_amdgcn_mfma_f32_16x16x32_bf16(th_hi[0], xh0, acc[nt], 0, 0, 0);
        acc[nt] = __builtin_amdgcn_mfma_f32_16x16x32_bf16(th_hi[0], xl0, acc[nt], 0, 0, 0);
        acc[nt] = __builtin_amdgcn_mfma_f32_16x16x32_bf16(th_lo[0], xh0, acc[nt], 0, 0, 0);
        acc[nt] = __builtin_amdgcn_mfma_f32_16x16x32_bf16(th_hi[1], xh1, acc[nt], 0, 0, 0);
        acc[nt] = __builtin_amdgcn_mfma_f32_16x16x32_bf16(th_hi[1], xl1, acc[nt], 0, 0, 0);
        acc[nt] = __builtin_amdgcn_mfma_f32_16x16x32_bf16(th_lo[1], xh1, acc[nt], 0, 0, 0);
    }

    // ---- softmax chain ----
    finish(acc, wg, len, lane, red_m[w], red_s[w]);
    __syncthreads();

    // ---- final: combine 4 wave-partials per l; log2 -> ln; finite sentinel ----
    if (tid < 128) {
        const int l = tid;
        float M = red_m[0][l];
        M = fmaxf(M, red_m[1][l]);
        M = fmaxf(M, red_m[2][l]);
        M = fmaxf(M, red_m[3][l]);
        const float S = red_s[0][l] * exp2_fast(red_m[0][l] - M)
                      + red_s[1][l] * exp2_fast(red_m[1][l] - M)
                      + red_s[2][l] * exp2_fast(red_m[2][l] - M)
                      + red_s[3][l] * exp2_fast(red_m[3][l] - M);
        const float o = LN2 * (M + log2_fast(S));
        out[(size_t)b * 128 + l] = (l < len) ? o : NEGV;
    }
}

extern "C" void kernel_launch(void* const* d_in, const int* in_sizes, int n_in,
                              void* d_out, int out_size, void* d_ws, size_t ws_size,
                              hipStream_t stream) {
    const float* x     = (const float*)d_in[0];
    const int*   lens  = (const int*)d_in[1];
    const float* theta = (const float*)d_in[2];
    const float* mw    = (const float*)d_in[3];
    float* out = (float*)d_out;
    const int B = in_sizes[1];  // 8192

    if (ws_size >= (size_t)WS_FLOATS_NEEDED * sizeof(float)) {
        float* ws = (float*)d_ws;
        prep_kernel<<<1, 64, 0, stream>>>(theta, mw, ws);
        mixed_logit_kernel<true><<<B, 256, 0, stream>>>(x, lens, theta, mw, ws, out);
    } else {
        mixed_logit_kernel<false><<<B, 256, 0, stream>>>(x, lens, theta, mw, nullptr, out);
    }
}